// Round 14
// baseline (54.667 us; speedup 1.0000x reference)
//
#include <hip/hip_runtime.h>
#include <math.h>

// out[n] = sum_k exp2( t[n,k] ),  t[n,k] = sum_{j<10} P[n,j]*G[k,j]
// P = (x0^2,x1^2,x2^2, x0x1,x0x2,x1x2, x0,x1,x2, 1)
// G = h*(A00,A11,A22), 2h*(A01,A02,A12), L2E*(b0,b1,b2), h*c + log2(amp), h=-0.5*log2(e)
//
// MFMA f16 split-2 trick (one mfma_f32_16x16x32_f16 per 16x16 tile):
//   A cols [0..31] = [Phi(10) | Phi(10) | Plo(10) | 0 0]
//   B rows [0..31] = [Ghi(10) | Glo(10) | Ghi(10) | 0 0]
//
// ROUND 14 KEY CHANGE: cvt-free Schraudolph exp2 (v_cvt_u32_f32 measured
// quarter-rate = the calibrated bottleneck of rounds 8-13).
//   u = t*2^23 + B  realized as:  v = fma(t, 2^14, B*2^-9 + 1.5*2^23)
//   -> float ulp=1 in [1.5*2^23, 2^24) does the int-convert for free:
//      bits(v) = 0x4B400000 + (u>>9)
//   v = max(v, 1.5*2^23)   (t <= -126.9, incl. -60000 pads -> exactly 0)
//   e_bits = (bits(v)<<9) + 0x80000000   (v_lshl_add_u32; 0x4B400000*512
//            == -0x80000000 mod 2^32)
//   acc += bitcast<float>(e_bits)
// All full-rate VALU: per value pk_fma+pk_max+lshl_add+add ~ 6cy vs 12.
// Quantization (u to mult. of 512) = 6e-5 rel, invisible under 3.8% ripple.

typedef _Float16 half8 __attribute__((ext_vector_type(8)));
typedef float    f32x4 __attribute__((ext_vector_type(4)));

#define PT       4    // point-tiles (16 points) per wave
#define WPB      4    // waves per block
#define KSPLIT   8    // gaussian-tile splits (blockIdx.y)
#define CHUNKMAX 16   // max k-tiles per split for the LDS path
#define LDSPAD   20   // LDS tiles allocated (chunk + prefetch overrun pad)

#define EXP_SCALE2 16384.0f       // 2^14
#define EXP_MAGIC  12582912.0f    // 1.5 * 2^23
// B = (127 - 0.0563)*2^23 = 1064880938;  bias2 = B/512 + MAGIC
#define EXP_BIAS2  14662757.58f

__global__ __launch_bounds__(256) void gmf_precompute(
        const float* __restrict__ means,
        const float* __restrict__ log_scales,
        const float* __restrict__ quats,
        const float* __restrict__ log_amps,
        _Float16* __restrict__ Bf, int K, int KT) {
    int k = blockIdx.x * blockDim.x + threadIdx.x;
    if (k >= KT * 16) return;

    float gc[10];
    if (k < K) {
        float qw = quats[4*k+0], qx = quats[4*k+1], qy = quats[4*k+2], qz = quats[4*k+3];
        float qn = rsqrtf(qw*qw + qx*qx + qy*qy + qz*qz);
        qw *= qn; qx *= qn; qy *= qn; qz *= qn;

        float r00 = 1.f - 2.f*(qy*qy + qz*qz);
        float r01 = 2.f*(qx*qy - qw*qz);
        float r02 = 2.f*(qx*qz + qw*qy);
        float r10 = 2.f*(qx*qy + qw*qz);
        float r11 = 1.f - 2.f*(qx*qx + qz*qz);
        float r12 = 2.f*(qy*qz - qw*qx);
        float r20 = 2.f*(qx*qz - qw*qy);
        float r21 = 2.f*(qy*qz + qw*qx);
        float r22 = 1.f - 2.f*(qx*qx + qy*qy);

        float s0 = fminf(fmaxf(expf(log_scales[3*k+0]), 1e-5f), 100.f);
        float s1 = fminf(fmaxf(expf(log_scales[3*k+1]), 1e-5f), 100.f);
        float s2 = fminf(fmaxf(expf(log_scales[3*k+2]), 1e-5f), 100.f);
        float v0 = s0*s0, v1 = s1*s1, v2 = s2*s2;

        float S00 = r00*r00*v0 + r01*r01*v1 + r02*r02*v2 + 1e-5f;
        float S11 = r10*r10*v0 + r11*r11*v1 + r12*r12*v2 + 1e-5f;
        float S22 = r20*r20*v0 + r21*r21*v1 + r22*r22*v2 + 1e-5f;
        float S01 = r00*r10*v0 + r01*r11*v1 + r02*r12*v2;
        float S02 = r00*r20*v0 + r01*r21*v1 + r02*r22*v2;
        float S12 = r10*r20*v0 + r11*r21*v1 + r12*r22*v2;

        float c00 = S11*S22 - S12*S12;
        float c01 = S02*S12 - S01*S22;
        float c02 = S01*S12 - S02*S11;
        float det = S00*c00 + S01*c01 + S02*c02;
        float id  = 1.f/det;
        float A00 = c00*id, A01 = c01*id, A02 = c02*id;
        float A11 = (S00*S22 - S02*S02)*id;
        float A12 = (S01*S02 - S00*S12)*id;
        float A22 = (S00*S11 - S01*S01)*id;

        float m0 = means[3*k+0], m1 = means[3*k+1], m2 = means[3*k+2];
        float b0 = A00*m0 + A01*m1 + A02*m2;
        float b1 = A01*m0 + A11*m1 + A12*m2;
        float b2 = A02*m0 + A12*m1 + A22*m2;
        float cc = b0*m0 + b1*m1 + b2*m2;

        float la = fminf(fmaxf(log_amps[k], -10.f), 6.f);
        const float L2E = 1.4426950408889634f;
        const float h = -0.5f * L2E;

        gc[0] = h*A00; gc[1] = h*A11; gc[2] = h*A22;
        gc[3] = 2.f*h*A01; gc[4] = 2.f*h*A02; gc[5] = 2.f*h*A12;
        gc[6] = L2E*b0; gc[7] = L2E*b1; gc[8] = L2E*b2;
        gc[9] = h*cc + L2E*la;
    } else {
        #pragma unroll
        for (int j = 0; j < 10; ++j) gc[j] = 0.f;
        gc[9] = -60000.f;   // pad gaussian -> clamps to exactly 0 in fast exp2
    }

    _Float16 gh[10], gl[10];
    #pragma unroll
    for (int j = 0; j < 10; ++j) {
        gh[j] = (_Float16)gc[j];
        gl[j] = (_Float16)(gc[j] - (float)gh[j]);
    }

    int kt = k >> 4, c = k & 15;
    _Float16* dst = Bf + (size_t)kt * 64 * 8;
    #pragma unroll 32
    for (int r = 0; r < 32; ++r) {
        int lg = r >> 3, j = r & 7;
        _Float16 v = (r < 10) ? gh[r]
                   : (r < 20) ? gl[r-10]
                   : (r < 30) ? gh[r-20]
                   : (_Float16)0.f;
        dst[((size_t)lg*16 + c)*8 + j] = v;
    }
}

// ---- shared A-fragment builder ----
__device__ __forceinline__ void gmf_build_afr(
        const float* __restrict__ x, int gwid, int lane, int N, int PTtot,
        half8* afr, int* pts) {
    int lr = lane & 15;
    int lg = lane >> 4;
    #pragma unroll
    for (int t = 0; t < PT; ++t) {
        int pt = gwid * PT + t;
        pts[t] = pt;
        int n = pt * 16 + lr;
        float x0 = 0.f, x1 = 0.f, x2 = 0.f;
        if (pt < PTtot && n < N) { x0 = x[3*n]; x1 = x[3*n+1]; x2 = x[3*n+2]; }

        float P0 = x0*x0, P1 = x1*x1, P2 = x2*x2;
        float P3 = x0*x1, P4 = x0*x2, P5 = x1*x2;

        _Float16 h0 = (_Float16)P0, h1 = (_Float16)P1, h2 = (_Float16)P2;
        _Float16 h3 = (_Float16)P3, h4 = (_Float16)P4, h5 = (_Float16)P5;
        _Float16 h6 = (_Float16)x0, h7 = (_Float16)x1, h8 = (_Float16)x2;
        _Float16 h9 = (_Float16)1.f;
        _Float16 l0 = (_Float16)(P0 - (float)h0), l1 = (_Float16)(P1 - (float)h1);
        _Float16 l2 = (_Float16)(P2 - (float)h2), l3 = (_Float16)(P3 - (float)h3);
        _Float16 l4 = (_Float16)(P4 - (float)h4), l5 = (_Float16)(P5 - (float)h5);
        _Float16 l6 = (_Float16)(x0 - (float)h6), l7 = (_Float16)(x1 - (float)h7);
        _Float16 l8 = (_Float16)(x2 - (float)h8), l9 = (_Float16)0.f;
        _Float16 z  = (_Float16)0.f;

        half8 a;
        if      (lg == 0) a = (half8){h0,h1,h2,h3,h4,h5,h6,h7};
        else if (lg == 1) a = (half8){h8,h9,h0,h1,h2,h3,h4,h5};
        else if (lg == 2) a = (half8){h6,h7,h8,h9,l0,l1,l2,l3};
        else              a = (half8){l4,l5,l6,l7,l8,l9,z,z};
        afr[t] = a;
    }
}

__device__ __forceinline__ void gmf_epilogue(
        const f32x4* acc, const int* pts,
        int lane, int N, int PTtot, float* __restrict__ dst_base) {
    int lr = lane & 15;
    int lg = lane >> 4;
    #pragma unroll
    for (int t = 0; t < PT; ++t) {
        f32x4 a = acc[t];
        #pragma unroll
        for (int m = 1; m <= 8; m <<= 1) {   // reduce over 16 cols
            a.x += __shfl_xor(a.x, m);
            a.y += __shfl_xor(a.y, m);
            a.z += __shfl_xor(a.z, m);
            a.w += __shfl_xor(a.w, m);
        }
        if (lr == 0 && pts[t] < PTtot) {
            int n0 = pts[t] * 16 + lg * 4;
            if (n0     < N) dst_base[n0]     = a.x;
            if (n0 + 1 < N) dst_base[n0 + 1] = a.y;
            if (n0 + 2 < N) dst_base[n0 + 2] = a.z;
            if (n0 + 3 < N) dst_base[n0 + 3] = a.w;
        }
    }
}

#define GMF_EXPACC(CC)                                                          \
    { _Pragma("unroll")                                                         \
      for (int t = 0; t < PT; ++t) {                                            \
          f32x4 v = __builtin_elementwise_fma((CC)[t], vscale, vbias);          \
          v = __builtin_elementwise_max(v, vmagic);                             \
          unsigned ex = (__float_as_uint(v.x) << 9) + 0x80000000u;              \
          unsigned ey = (__float_as_uint(v.y) << 9) + 0x80000000u;              \
          unsigned ez = (__float_as_uint(v.z) << 9) + 0x80000000u;              \
          unsigned ew = (__float_as_uint(v.w) << 9) + 0x80000000u;              \
          acc[t].x += __uint_as_float(ex);                                      \
          acc[t].y += __uint_as_float(ey);                                      \
          acc[t].z += __uint_as_float(ez);                                      \
          acc[t].w += __uint_as_float(ew);                                      \
      } }

#define GMF_MFMA4(DST, BB)                                                      \
    { _Pragma("unroll")                                                         \
      for (int t = 0; t < PT; ++t)                                              \
          (DST)[t] = __builtin_amdgcn_mfma_f32_16x16x32_f16(                    \
              afr[t], (BB), czero, 0, 0, 0); }

// LDS-staged main: all WPB waves share the blockIdx.y k-chunk (<= CHUNKMAX tiles).
__global__ __launch_bounds__(256, 2) void gmf_main_lds(
        const float* __restrict__ x,
        const half8* __restrict__ Bf,
        float* __restrict__ partial,   // [ksplit][N]
        int N, int KT, int PTtot, int ksplit) {
    __shared__ half8 lbs[LDSPAD * 64];   // 20 KiB

    int tid  = threadIdx.x;
    int lane = tid & 63;
    int wid  = tid >> 6;
    int gwid = blockIdx.x * WPB + wid;

    int split = blockIdx.y;
    int chunk = (KT + ksplit - 1) / ksplit;
    int kbeg = split * chunk;
    int kend = min(KT, kbeg + chunk);
    int nk = kend - kbeg;                // 1..CHUNKMAX

    // ---- stage B chunk into LDS (coalesced), then barrier ----
    {
        const half8* bg = Bf + (size_t)kbeg * 64;
        int tot = nk * 64;
        for (int i = tid; i < tot; i += 256) lbs[i] = bg[i];
    }
    __syncthreads();

    half8 afr[PT];
    f32x4 acc[PT];
    int   pts[PT];
    gmf_build_afr(x, gwid, lane, N, PTtot, afr, pts);
    #pragma unroll
    for (int t = 0; t < PT; ++t) acc[t] = (f32x4){0.f, 0.f, 0.f, 0.f};

    bool any_valid = (gwid * PT) < PTtot;
    if (any_valid) {
        float z0 = 0.f, z1 = 0.f, z2 = 0.f, z3 = 0.f;
        asm volatile("" : "+v"(z0), "+v"(z1), "+v"(z2), "+v"(z3));
        const f32x4 czero = {z0, z1, z2, z3};
        const f32x4 vscale = {EXP_SCALE2, EXP_SCALE2, EXP_SCALE2, EXP_SCALE2};
        const f32x4 vbias  = {EXP_BIAS2,  EXP_BIAS2,  EXP_BIAS2,  EXP_BIAS2};
        const f32x4 vmagic = {EXP_MAGIC,  EXP_MAGIC,  EXP_MAGIC,  EXP_MAGIC};

        // LDS reads below may index up to nk+3 < LDSPAD: in-bounds, values unused.
        half8 bc = lbs[lane];
        half8 p1 = lbs[64 + lane];
        half8 p2 = lbs[128 + lane];

        f32x4 cP[PT], cQ[PT];
        GMF_MFMA4(cP, bc)

        int j = 1;
        for (; j + 1 < nk; j += 2) {
            half8 bA = p1;
            half8 bB = p2;
            p1 = lbs[(j + 2) * 64 + lane];
            p2 = lbs[(j + 3) * 64 + lane];
            GMF_MFMA4(cQ, bA)     // issue next MFMAs...
            GMF_EXPACC(cP)        // ...prev exp/acc under their shadow
            GMF_MFMA4(cP, bB)
            GMF_EXPACC(cQ)
        }
        if (j < nk) {             // even nk tail
            GMF_MFMA4(cQ, p1)
            GMF_EXPACC(cP)
            GMF_EXPACC(cQ)
        } else {                  // odd nk
            GMF_EXPACC(cP)
        }
        gmf_epilogue(acc, pts, lane, N, PTtot, partial + (size_t)split * N);
    }
}

// Generic fallback (global B feed) for chunk > CHUNKMAX.
__global__ __launch_bounds__(256, 2) void gmf_main_g(
        const float* __restrict__ x,
        const half8* __restrict__ Bf,
        float* __restrict__ partial,
        int N, int KT, int PTtot, int ksplit) {
    int tid  = threadIdx.x;
    int lane = tid & 63;
    int wid  = tid >> 6;
    int gwid = blockIdx.x * WPB + wid;

    int split = blockIdx.y;
    int chunk = (KT + ksplit - 1) / ksplit;
    int kbeg = split * chunk;
    int kend = min(KT, kbeg + chunk);

    half8 afr[PT];
    f32x4 acc[PT];
    int   pts[PT];
    gmf_build_afr(x, gwid, lane, N, PTtot, afr, pts);
    #pragma unroll
    for (int t = 0; t < PT; ++t) acc[t] = (f32x4){0.f, 0.f, 0.f, 0.f};

    if (gwid * PT >= PTtot) return;

    float z0 = 0.f, z1 = 0.f, z2 = 0.f, z3 = 0.f;
    asm volatile("" : "+v"(z0), "+v"(z1), "+v"(z2), "+v"(z3));
    const f32x4 czero = {z0, z1, z2, z3};
    const f32x4 vscale = {EXP_SCALE2, EXP_SCALE2, EXP_SCALE2, EXP_SCALE2};
    const f32x4 vbias  = {EXP_BIAS2,  EXP_BIAS2,  EXP_BIAS2,  EXP_BIAS2};
    const f32x4 vmagic = {EXP_MAGIC,  EXP_MAGIC,  EXP_MAGIC,  EXP_MAGIC};

    if (kbeg < kend) {
        const half8* bp = Bf + lane;
        half8 bc = bp[(size_t)kbeg * 64];
        half8 p1 = bp[(size_t)(kbeg + 1) * 64];
        half8 p2 = bp[(size_t)(kbeg + 2) * 64];

        f32x4 cP[PT], cQ[PT];
        GMF_MFMA4(cP, bc)

        int kt = kbeg + 1;
        for (; kt + 1 < kend; kt += 2) {
            half8 bA = p1;
            half8 bB = p2;
            p1 = bp[(size_t)(kt + 2) * 64];
            p2 = bp[(size_t)(kt + 3) * 64];
            GMF_MFMA4(cQ, bA)
            GMF_EXPACC(cP)
            GMF_MFMA4(cP, bB)
            GMF_EXPACC(cQ)
        }
        if (kt < kend) {
            GMF_MFMA4(cQ, p1)
            GMF_EXPACC(cP)
            GMF_EXPACC(cQ)
        } else {
            GMF_EXPACC(cP)
        }
    }
    gmf_epilogue(acc, pts, lane, N, PTtot, partial + (size_t)split * N);
}

__global__ __launch_bounds__(256) void gmf_reduce(
        const float* __restrict__ partial,
        float* __restrict__ out, int N, int ksplit) {
    int j = blockIdx.x * blockDim.x + threadIdx.x;
    int n0 = 4 * j;
    if (n0 >= N) return;
    if (n0 + 3 < N) {
        float4 s = {0.f, 0.f, 0.f, 0.f};
        for (int sp = 0; sp < ksplit; ++sp) {
            float4 v = *(const float4*)(partial + (size_t)sp * N + n0);
            s.x += v.x; s.y += v.y; s.z += v.z; s.w += v.w;
        }
        *(float4*)(out + n0) = s;
    } else {
        for (int n = n0; n < N; ++n) {
            float s = 0.f;
            for (int sp = 0; sp < ksplit; ++sp) s += partial[(size_t)sp * N + n];
            out[n] = s;
        }
    }
}

extern "C" void kernel_launch(void* const* d_in, const int* in_sizes, int n_in,
                              void* d_out, int out_size, void* d_ws, size_t ws_size,
                              hipStream_t stream) {
    const float* x          = (const float*)d_in[0];
    const float* means      = (const float*)d_in[1];
    const float* log_scales = (const float*)d_in[2];
    const float* quats      = (const float*)d_in[3];
    const float* log_amps   = (const float*)d_in[4];
    float* out = (float*)d_out;

    int K = in_sizes[4];
    int N = out_size;
    int KT = (K + 15) / 16;
    int PTtot = (N + 15) / 16;

    // +2 tiles padding (fallback kernel's unguarded prefetch).
    size_t b_bytes = (((size_t)(KT + 2)) * 64 * 8 * sizeof(_Float16) + 255) & ~(size_t)255;
    _Float16* Bf = (_Float16*)d_ws;

    int ksplit = 1;
    for (int ks = KSPLIT; ks >= 2; ks >>= 1) {
        if (b_bytes + (size_t)ks * N * sizeof(float) <= ws_size) { ksplit = ks; break; }
    }
    bool use_partial = (ksplit > 1);

    gmf_precompute<<<(KT*16 + 255) / 256, 256, 0, stream>>>(
        means, log_scales, quats, log_amps, Bf, K, KT);

    int waves  = (PTtot + PT - 1) / PT;
    int blocks = (waves + WPB - 1) / WPB;

    if (use_partial) {
        float* partial = (float*)((char*)d_ws + b_bytes);
        dim3 grid(blocks, ksplit);
        int chunk = (KT + ksplit - 1) / ksplit;
        if (chunk <= CHUNKMAX)
            gmf_main_lds<<<grid, 256, 0, stream>>>(x, (const half8*)Bf, partial,
                                                   N, KT, PTtot, ksplit);
        else
            gmf_main_g<<<grid, 256, 0, stream>>>(x, (const half8*)Bf, partial,
                                                 N, KT, PTtot, ksplit);
        int nquads = (N + 3) / 4;
        gmf_reduce<<<(nquads + 255) / 256, 256, 0, stream>>>(partial, out, N, ksplit);
    } else {
        gmf_main_g<<<dim3(blocks, 1), 256, 0, stream>>>(x, (const half8*)Bf, out,
                                                        N, KT, PTtot, 1);
    }
}

// Round 15
// 51.179 us; speedup vs baseline: 1.0681x; 1.0681x over previous
//
#include <hip/hip_runtime.h>
#include <math.h>

// out[n] = sum_k exp2( t[n,k] ),  t[n,k] = sum_{j<10} P[n,j]*G[k,j]
// P = (x0^2,x1^2,x2^2, x0x1,x0x2,x1x2, x0,x1,x2, 1)
// G = h*(A00,A11,A22), 2h*(A01,A02,A12), L2E*(b0,b1,b2), h*c + log2(amp), h=-0.5*log2(e)
//
// MFMA f16 split-2 trick (one mfma_f32_16x16x32_f16 per 16x16 tile):
//   A cols [0..31] = [Phi(10) | Phi(10) | Plo(10) | 0 0]
//   B rows [0..31] = [Ghi(10) | Glo(10) | Ghi(10) | 0 0]
//
// exp2 via mean-zero Schraudolph (round-13 form, cvt is full-rate):
//   y = fma(t, 2^23, B); u = v_cvt_u32_f32(y) [HW-saturating: y<0 -> 0,
//   incl. -60000 pad gaussians]; acc += bitcast<float>(u).
//
// ROUND 15 KEY CHANGE: PT=1 minimal-register kernel (afr 4 + acc 4 + cP/cQ 8
// + B ~8 ~= 30 VGPR) + __launch_bounds__(256,8) -> 8 waves/SIMD, LDS B-chunk
// (20KB -> 8 blocks/CU) = ~100% occupancy. Theory: rounds 9-14 were
// dependency-latency bound at 4 waves/SIMD; double TLP covers the stalls
// that ILP (r12) and LDS (r13) could not.

typedef _Float16 half8 __attribute__((ext_vector_type(8)));
typedef float    f32x4 __attribute__((ext_vector_type(4)));

#define WPB      4    // waves per block (1 point-tile per wave)
#define KSPLIT   8    // gaussian-tile splits (blockIdx.y)
#define CHUNKMAX 16   // max k-tiles per split for the LDS path
#define LDSPAD   20   // LDS tiles allocated (chunk + prefetch overrun pad)

#define EXP_SCALE 8388608.0f        // 2^23
#define EXP_BIAS  1064880938.0f     // (127 - 0.0563) * 2^23, mean-zero bias

__device__ __forceinline__ unsigned cvt_u32_sat(float y) {
    unsigned u;
    asm("v_cvt_u32_f32 %0, %1" : "=v"(u) : "v"(y));   // saturates: y<0 -> 0
    return u;
}

__global__ __launch_bounds__(256) void gmf_precompute(
        const float* __restrict__ means,
        const float* __restrict__ log_scales,
        const float* __restrict__ quats,
        const float* __restrict__ log_amps,
        _Float16* __restrict__ Bf, int K, int KT) {
    int k = blockIdx.x * blockDim.x + threadIdx.x;
    if (k >= KT * 16) return;

    float gc[10];
    if (k < K) {
        float qw = quats[4*k+0], qx = quats[4*k+1], qy = quats[4*k+2], qz = quats[4*k+3];
        float qn = rsqrtf(qw*qw + qx*qx + qy*qy + qz*qz);
        qw *= qn; qx *= qn; qy *= qn; qz *= qn;

        float r00 = 1.f - 2.f*(qy*qy + qz*qz);
        float r01 = 2.f*(qx*qy - qw*qz);
        float r02 = 2.f*(qx*qz + qw*qy);
        float r10 = 2.f*(qx*qy + qw*qz);
        float r11 = 1.f - 2.f*(qx*qx + qz*qz);
        float r12 = 2.f*(qy*qz - qw*qx);
        float r20 = 2.f*(qx*qz - qw*qy);
        float r21 = 2.f*(qy*qz + qw*qx);
        float r22 = 1.f - 2.f*(qx*qx + qy*qy);

        float s0 = fminf(fmaxf(expf(log_scales[3*k+0]), 1e-5f), 100.f);
        float s1 = fminf(fmaxf(expf(log_scales[3*k+1]), 1e-5f), 100.f);
        float s2 = fminf(fmaxf(expf(log_scales[3*k+2]), 1e-5f), 100.f);
        float v0 = s0*s0, v1 = s1*s1, v2 = s2*s2;

        float S00 = r00*r00*v0 + r01*r01*v1 + r02*r02*v2 + 1e-5f;
        float S11 = r10*r10*v0 + r11*r11*v1 + r12*r12*v2 + 1e-5f;
        float S22 = r20*r20*v0 + r21*r21*v1 + r22*r22*v2 + 1e-5f;
        float S01 = r00*r10*v0 + r01*r11*v1 + r02*r12*v2;
        float S02 = r00*r20*v0 + r01*r21*v1 + r02*r22*v2;
        float S12 = r10*r20*v0 + r11*r21*v1 + r12*r22*v2;

        float c00 = S11*S22 - S12*S12;
        float c01 = S02*S12 - S01*S22;
        float c02 = S01*S12 - S02*S11;
        float det = S00*c00 + S01*c01 + S02*c02;
        float id  = 1.f/det;
        float A00 = c00*id, A01 = c01*id, A02 = c02*id;
        float A11 = (S00*S22 - S02*S02)*id;
        float A12 = (S01*S02 - S00*S12)*id;
        float A22 = (S00*S11 - S01*S01)*id;

        float m0 = means[3*k+0], m1 = means[3*k+1], m2 = means[3*k+2];
        float b0 = A00*m0 + A01*m1 + A02*m2;
        float b1 = A01*m0 + A11*m1 + A12*m2;
        float b2 = A02*m0 + A12*m1 + A22*m2;
        float cc = b0*m0 + b1*m1 + b2*m2;

        float la = fminf(fmaxf(log_amps[k], -10.f), 6.f);
        const float L2E = 1.4426950408889634f;
        const float h = -0.5f * L2E;

        gc[0] = h*A00; gc[1] = h*A11; gc[2] = h*A22;
        gc[3] = 2.f*h*A01; gc[4] = 2.f*h*A02; gc[5] = 2.f*h*A12;
        gc[6] = L2E*b0; gc[7] = L2E*b1; gc[8] = L2E*b2;
        gc[9] = h*cc + L2E*la;
    } else {
        #pragma unroll
        for (int j = 0; j < 10; ++j) gc[j] = 0.f;
        gc[9] = -60000.f;   // pad gaussian -> saturates to 0 in fast exp2
    }

    _Float16 gh[10], gl[10];
    #pragma unroll
    for (int j = 0; j < 10; ++j) {
        gh[j] = (_Float16)gc[j];
        gl[j] = (_Float16)(gc[j] - (float)gh[j]);
    }

    int kt = k >> 4, c = k & 15;
    _Float16* dst = Bf + (size_t)kt * 64 * 8;
    #pragma unroll 32
    for (int r = 0; r < 32; ++r) {
        int lg = r >> 3, j = r & 7;
        _Float16 v = (r < 10) ? gh[r]
                   : (r < 20) ? gl[r-10]
                   : (r < 30) ? gh[r-20]
                   : (_Float16)0.f;
        dst[((size_t)lg*16 + c)*8 + j] = v;
    }
}

// ---- single-tile A-fragment builder ----
__device__ __forceinline__ half8 gmf_build_afr1(
        const float* __restrict__ x, int pt, int lane, int N, int PTtot) {
    int lr = lane & 15;
    int lg = lane >> 4;
    int n = pt * 16 + lr;
    float x0 = 0.f, x1 = 0.f, x2 = 0.f;
    if (pt < PTtot && n < N) { x0 = x[3*n]; x1 = x[3*n+1]; x2 = x[3*n+2]; }

    float P0 = x0*x0, P1 = x1*x1, P2 = x2*x2;
    float P3 = x0*x1, P4 = x0*x2, P5 = x1*x2;

    _Float16 h0 = (_Float16)P0, h1 = (_Float16)P1, h2 = (_Float16)P2;
    _Float16 h3 = (_Float16)P3, h4 = (_Float16)P4, h5 = (_Float16)P5;
    _Float16 h6 = (_Float16)x0, h7 = (_Float16)x1, h8 = (_Float16)x2;
    _Float16 h9 = (_Float16)1.f;
    _Float16 l0 = (_Float16)(P0 - (float)h0), l1 = (_Float16)(P1 - (float)h1);
    _Float16 l2 = (_Float16)(P2 - (float)h2), l3 = (_Float16)(P3 - (float)h3);
    _Float16 l4 = (_Float16)(P4 - (float)h4), l5 = (_Float16)(P5 - (float)h5);
    _Float16 l6 = (_Float16)(x0 - (float)h6), l7 = (_Float16)(x1 - (float)h7);
    _Float16 l8 = (_Float16)(x2 - (float)h8), l9 = (_Float16)0.f;
    _Float16 z  = (_Float16)0.f;

    half8 a;
    if      (lg == 0) a = (half8){h0,h1,h2,h3,h4,h5,h6,h7};
    else if (lg == 1) a = (half8){h8,h9,h0,h1,h2,h3,h4,h5};
    else if (lg == 2) a = (half8){h6,h7,h8,h9,l0,l1,l2,l3};
    else              a = (half8){l4,l5,l6,l7,l8,l9,z,z};
    return a;
}

__device__ __forceinline__ void gmf_epilogue1(
        f32x4 a, int pt, int lane, int N, int PTtot, float* __restrict__ dst_base) {
    int lr = lane & 15;
    int lg = lane >> 4;
    #pragma unroll
    for (int m = 1; m <= 8; m <<= 1) {   // reduce over 16 cols
        a.x += __shfl_xor(a.x, m);
        a.y += __shfl_xor(a.y, m);
        a.z += __shfl_xor(a.z, m);
        a.w += __shfl_xor(a.w, m);
    }
    if (lr == 0 && pt < PTtot) {
        int n0 = pt * 16 + lg * 4;
        if (n0     < N) dst_base[n0]     = a.x;
        if (n0 + 1 < N) dst_base[n0 + 1] = a.y;
        if (n0 + 2 < N) dst_base[n0 + 2] = a.z;
        if (n0 + 3 < N) dst_base[n0 + 3] = a.w;
    }
}

#define GMF_EXPACC(CC)                                                          \
    {                                                                           \
        f32x4 y = __builtin_elementwise_fma((CC), vscale, vbias);               \
        acc.x += __uint_as_float(cvt_u32_sat(y.x));                             \
        acc.y += __uint_as_float(cvt_u32_sat(y.y));                             \
        acc.z += __uint_as_float(cvt_u32_sat(y.z));                             \
        acc.w += __uint_as_float(cvt_u32_sat(y.w));                             \
    }

// LDS-staged main, 1 tile/wave, min registers, 8 waves/SIMD target.
__global__ __launch_bounds__(256, 8) void gmf_main_lds(
        const float* __restrict__ x,
        const half8* __restrict__ Bf,
        float* __restrict__ partial,   // [ksplit][N]
        int N, int KT, int PTtot, int ksplit) {
    __shared__ half8 lbs[LDSPAD * 64];   // 20 KiB -> 8 blocks/CU

    int tid  = threadIdx.x;
    int lane = tid & 63;
    int wid  = tid >> 6;
    int pt   = blockIdx.x * WPB + wid;   // one point-tile per wave

    int split = blockIdx.y;
    int chunk = (KT + ksplit - 1) / ksplit;
    int kbeg = split * chunk;
    int kend = min(KT, kbeg + chunk);
    int nk = kend - kbeg;                // 1..CHUNKMAX

    // ---- stage B chunk into LDS (coalesced), then barrier ----
    {
        const half8* bg = Bf + (size_t)kbeg * 64;
        int tot = nk * 64;
        for (int i = tid; i < tot; i += 256) lbs[i] = bg[i];
    }
    __syncthreads();

    if (pt >= PTtot) return;

    half8 afr = gmf_build_afr1(x, pt, lane, N, PTtot);
    f32x4 acc = {0.f, 0.f, 0.f, 0.f};
    const f32x4 czero  = {0.f, 0.f, 0.f, 0.f};
    const f32x4 vscale = {EXP_SCALE, EXP_SCALE, EXP_SCALE, EXP_SCALE};
    const f32x4 vbias  = {EXP_BIAS,  EXP_BIAS,  EXP_BIAS,  EXP_BIAS};

    // Two-stage pipeline: EXPACC of tile i under shadow of tile i+1's MFMA.
    // LDS prefetch indices reach at most nk+1 <= 17 < LDSPAD (values unused).
    half8 b1 = lbs[lane];                 // tile 0
    f32x4 cP = __builtin_amdgcn_mfma_f32_16x16x32_f16(afr, b1, czero, 0, 0, 0);
    b1 = lbs[64 + lane];                  // tile 1 (pad-safe)
    f32x4 cQ;

    int j = 1;
    for (; j + 1 < nk; j += 2) {
        half8 bA = b1;                          // tile j
        half8 bB = lbs[(j + 1) * 64 + lane];    // tile j+1
        b1 = lbs[(j + 2) * 64 + lane];          // tile j+2 (pad-safe)
        cQ = __builtin_amdgcn_mfma_f32_16x16x32_f16(afr, bA, czero, 0, 0, 0);
        GMF_EXPACC(cP)
        cP = __builtin_amdgcn_mfma_f32_16x16x32_f16(afr, bB, czero, 0, 0, 0);
        GMF_EXPACC(cQ)
    }
    if (j < nk) {                         // even nk: one leftover tile in b1
        cQ = __builtin_amdgcn_mfma_f32_16x16x32_f16(afr, b1, czero, 0, 0, 0);
        GMF_EXPACC(cP)
        GMF_EXPACC(cQ)
    } else {                              // odd nk
        GMF_EXPACC(cP)
    }

    gmf_epilogue1(acc, pt, lane, N, PTtot, partial + (size_t)split * N);
}

// Generic fallback (global B feed) for chunk > CHUNKMAX. 1 tile/wave.
__global__ __launch_bounds__(256, 4) void gmf_main_g(
        const float* __restrict__ x,
        const half8* __restrict__ Bf,
        float* __restrict__ partial,
        int N, int KT, int PTtot, int ksplit) {
    int tid  = threadIdx.x;
    int lane = tid & 63;
    int wid  = tid >> 6;
    int pt   = blockIdx.x * WPB + wid;

    int split = blockIdx.y;
    int chunk = (KT + ksplit - 1) / ksplit;
    int kbeg = split * chunk;
    int kend = min(KT, kbeg + chunk);

    if (pt >= PTtot) return;

    half8 afr = gmf_build_afr1(x, pt, lane, N, PTtot);
    f32x4 acc = {0.f, 0.f, 0.f, 0.f};
    const f32x4 czero  = {0.f, 0.f, 0.f, 0.f};
    const f32x4 vscale = {EXP_SCALE, EXP_SCALE, EXP_SCALE, EXP_SCALE};
    const f32x4 vbias  = {EXP_BIAS,  EXP_BIAS,  EXP_BIAS,  EXP_BIAS};

    if (kbeg < kend) {
        const half8* bp = Bf + lane;
        half8 b1 = bp[(size_t)kbeg * 64];
        f32x4 cP = __builtin_amdgcn_mfma_f32_16x16x32_f16(afr, b1, czero, 0, 0, 0);
        b1 = bp[(size_t)(kbeg + 1) * 64];   // Bf padded +2 tiles: in-bounds
        f32x4 cQ;

        int kt = kbeg + 1;
        for (; kt + 1 < kend; kt += 2) {
            half8 bA = b1;
            half8 bB = bp[(size_t)(kt + 1) * 64];
            b1 = bp[(size_t)(kt + 2) * 64];
            cQ = __builtin_amdgcn_mfma_f32_16x16x32_f16(afr, bA, czero, 0, 0, 0);
            GMF_EXPACC(cP)
            cP = __builtin_amdgcn_mfma_f32_16x16x32_f16(afr, bB, czero, 0, 0, 0);
            GMF_EXPACC(cQ)
        }
        if (kt < kend) {
            cQ = __builtin_amdgcn_mfma_f32_16x16x32_f16(afr, b1, czero, 0, 0, 0);
            GMF_EXPACC(cP)
            GMF_EXPACC(cQ)
        } else {
            GMF_EXPACC(cP)
        }
    }
    gmf_epilogue1(acc, pt, lane, N, PTtot, partial + (size_t)split * N);
}

__global__ __launch_bounds__(256) void gmf_reduce(
        const float* __restrict__ partial,
        float* __restrict__ out, int N, int ksplit) {
    int j = blockIdx.x * blockDim.x + threadIdx.x;
    int n0 = 4 * j;
    if (n0 >= N) return;
    if (n0 + 3 < N) {
        float4 s = {0.f, 0.f, 0.f, 0.f};
        for (int sp = 0; sp < ksplit; ++sp) {
            float4 v = *(const float4*)(partial + (size_t)sp * N + n0);
            s.x += v.x; s.y += v.y; s.z += v.z; s.w += v.w;
        }
        *(float4*)(out + n0) = s;
    } else {
        for (int n = n0; n < N; ++n) {
            float s = 0.f;
            for (int sp = 0; sp < ksplit; ++sp) s += partial[(size_t)sp * N + n];
            out[n] = s;
        }
    }
}

extern "C" void kernel_launch(void* const* d_in, const int* in_sizes, int n_in,
                              void* d_out, int out_size, void* d_ws, size_t ws_size,
                              hipStream_t stream) {
    const float* x          = (const float*)d_in[0];
    const float* means      = (const float*)d_in[1];
    const float* log_scales = (const float*)d_in[2];
    const float* quats      = (const float*)d_in[3];
    const float* log_amps   = (const float*)d_in[4];
    float* out = (float*)d_out;

    int K = in_sizes[4];
    int N = out_size;
    int KT = (K + 15) / 16;
    int PTtot = (N + 15) / 16;

    // +2 tiles padding (fallback kernel's unguarded prefetch).
    size_t b_bytes = (((size_t)(KT + 2)) * 64 * 8 * sizeof(_Float16) + 255) & ~(size_t)255;
    _Float16* Bf = (_Float16*)d_ws;

    int ksplit = 1;
    for (int ks = KSPLIT; ks >= 2; ks >>= 1) {
        if (b_bytes + (size_t)ks * N * sizeof(float) <= ws_size) { ksplit = ks; break; }
    }
    bool use_partial = (ksplit > 1);

    gmf_precompute<<<(KT*16 + 255) / 256, 256, 0, stream>>>(
        means, log_scales, quats, log_amps, Bf, K, KT);

    int blocks = (PTtot + WPB - 1) / WPB;   // one tile per wave

    if (use_partial) {
        float* partial = (float*)((char*)d_ws + b_bytes);
        dim3 grid(blocks, ksplit);
        int chunk = (KT + ksplit - 1) / ksplit;
        if (chunk <= CHUNKMAX)
            gmf_main_lds<<<grid, 256, 0, stream>>>(x, (const half8*)Bf, partial,
                                                   N, KT, PTtot, ksplit);
        else
            gmf_main_g<<<grid, 256, 0, stream>>>(x, (const half8*)Bf, partial,
                                                 N, KT, PTtot, ksplit);
        int nquads = (N + 3) / 4;
        gmf_reduce<<<(nquads + 255) / 256, 256, 0, stream>>>(partial, out, N, ksplit);
    } else {
        gmf_main_g<<<dim3(blocks, 1), 256, 0, stream>>>(x, (const half8*)Bf, out,
                                                        N, KT, PTtot, 1);
    }
}

// Round 16
// 42.744 us; speedup vs baseline: 1.2789x; 1.1973x over previous
//
#include <hip/hip_runtime.h>
#include <math.h>

// out[n] = sum_k exp2( t[n,k] ),  t[n,k] = sum_{j<10} P[n,j]*G[k,j]
// P = (x0^2,x1^2,x2^2, x0x1,x0x2,x1x2, x0,x1,x2, 1)
// G = h*(A00,A11,A22), 2h*(A01,A02,A12), L2E*(b0,b1,b2), h*c + log2(amp), h=-0.5*log2(e)
//
// MFMA f16 split-2 trick (one mfma_f32_16x16x32_f16 per 16x16 tile):
//   A cols [0..31] = [Phi(10) | Phi(10) | Plo(10) | 0 0]
//   B rows [0..31] = [Ghi(10) | Glo(10) | Ghi(10) | 0 0]
//
// exp2 via mean-zero Schraudolph: y = fma(t,2^23,B); v_cvt_u32_f32 saturates
// y<0 -> 0 (incl. -60000 pad gaussians); acc += bitcast<float>(u).
//
// ROUND 16 KEY CHANGE: NO k-split. One wave owns one point-tile for ALL K:
// 8192 waves = 8/SIMD (launch_bounds(256,8)), afr-build and epilogue run ONCE
// per wave (was 8x), no partial buffer, no reduce kernel. B streamed through
// one 18-tile LDS buffer in chunks of 16 via global_load_lds (0 staging
// VGPRs); __syncthreads() pairs give the implicit vmcnt-drain ordering.
// Theory: r9-r15's persistent ~26us VALU-busy was ~40% per-(wave x split)
// fixed overhead; amortizing it 8x is the remaining source-level lever.

typedef _Float16 half8 __attribute__((ext_vector_type(8)));
typedef float    f32x4 __attribute__((ext_vector_type(4)));

#define WPB      4    // waves per block (1 point-tile per wave)
#define CHUNK    16   // k-tiles staged per LDS refill
#define LDSTILES 18   // LDS tiles allocated (CHUNK + 2 prefetch-overrun pad)

#define EXP_SCALE 8388608.0f        // 2^23
#define EXP_BIAS  1064880938.0f     // (127 - 0.0563) * 2^23, mean-zero bias

__device__ __forceinline__ unsigned cvt_u32_sat(float y) {
    unsigned u;
    asm("v_cvt_u32_f32 %0, %1" : "=v"(u) : "v"(y));   // saturates: y<0 -> 0
    return u;
}

__global__ __launch_bounds__(256) void gmf_precompute(
        const float* __restrict__ means,
        const float* __restrict__ log_scales,
        const float* __restrict__ quats,
        const float* __restrict__ log_amps,
        _Float16* __restrict__ Bf, int K, int KT) {
    int k = blockIdx.x * blockDim.x + threadIdx.x;
    if (k >= KT * 16) return;

    float gc[10];
    if (k < K) {
        float qw = quats[4*k+0], qx = quats[4*k+1], qy = quats[4*k+2], qz = quats[4*k+3];
        float qn = rsqrtf(qw*qw + qx*qx + qy*qy + qz*qz);
        qw *= qn; qx *= qn; qy *= qn; qz *= qn;

        float r00 = 1.f - 2.f*(qy*qy + qz*qz);
        float r01 = 2.f*(qx*qy - qw*qz);
        float r02 = 2.f*(qx*qz + qw*qy);
        float r10 = 2.f*(qx*qy + qw*qz);
        float r11 = 1.f - 2.f*(qx*qx + qz*qz);
        float r12 = 2.f*(qy*qz - qw*qx);
        float r20 = 2.f*(qx*qz - qw*qy);
        float r21 = 2.f*(qy*qz + qw*qx);
        float r22 = 1.f - 2.f*(qx*qx + qy*qy);

        float s0 = fminf(fmaxf(expf(log_scales[3*k+0]), 1e-5f), 100.f);
        float s1 = fminf(fmaxf(expf(log_scales[3*k+1]), 1e-5f), 100.f);
        float s2 = fminf(fmaxf(expf(log_scales[3*k+2]), 1e-5f), 100.f);
        float v0 = s0*s0, v1 = s1*s1, v2 = s2*s2;

        float S00 = r00*r00*v0 + r01*r01*v1 + r02*r02*v2 + 1e-5f;
        float S11 = r10*r10*v0 + r11*r11*v1 + r12*r12*v2 + 1e-5f;
        float S22 = r20*r20*v0 + r21*r21*v1 + r22*r22*v2 + 1e-5f;
        float S01 = r00*r10*v0 + r01*r11*v1 + r02*r12*v2;
        float S02 = r00*r20*v0 + r01*r21*v1 + r02*r22*v2;
        float S12 = r10*r20*v0 + r11*r21*v1 + r12*r22*v2;

        float c00 = S11*S22 - S12*S12;
        float c01 = S02*S12 - S01*S22;
        float c02 = S01*S12 - S02*S11;
        float det = S00*c00 + S01*c01 + S02*c02;
        float id  = 1.f/det;
        float A00 = c00*id, A01 = c01*id, A02 = c02*id;
        float A11 = (S00*S22 - S02*S02)*id;
        float A12 = (S01*S02 - S00*S12)*id;
        float A22 = (S00*S11 - S01*S01)*id;

        float m0 = means[3*k+0], m1 = means[3*k+1], m2 = means[3*k+2];
        float b0 = A00*m0 + A01*m1 + A02*m2;
        float b1 = A01*m0 + A11*m1 + A12*m2;
        float b2 = A02*m0 + A12*m1 + A22*m2;
        float cc = b0*m0 + b1*m1 + b2*m2;

        float la = fminf(fmaxf(log_amps[k], -10.f), 6.f);
        const float L2E = 1.4426950408889634f;
        const float h = -0.5f * L2E;

        gc[0] = h*A00; gc[1] = h*A11; gc[2] = h*A22;
        gc[3] = 2.f*h*A01; gc[4] = 2.f*h*A02; gc[5] = 2.f*h*A12;
        gc[6] = L2E*b0; gc[7] = L2E*b1; gc[8] = L2E*b2;
        gc[9] = h*cc + L2E*la;
    } else {
        #pragma unroll
        for (int j = 0; j < 10; ++j) gc[j] = 0.f;
        gc[9] = -60000.f;   // pad gaussian -> saturates to 0 in fast exp2
    }

    _Float16 gh[10], gl[10];
    #pragma unroll
    for (int j = 0; j < 10; ++j) {
        gh[j] = (_Float16)gc[j];
        gl[j] = (_Float16)(gc[j] - (float)gh[j]);
    }

    int kt = k >> 4, c = k & 15;
    _Float16* dst = Bf + (size_t)kt * 64 * 8;
    #pragma unroll 32
    for (int r = 0; r < 32; ++r) {
        int lg = r >> 3, j = r & 7;
        _Float16 v = (r < 10) ? gh[r]
                   : (r < 20) ? gl[r-10]
                   : (r < 30) ? gh[r-20]
                   : (_Float16)0.f;
        dst[((size_t)lg*16 + c)*8 + j] = v;
    }
}

// ---- single-tile A-fragment builder ----
__device__ __forceinline__ half8 gmf_build_afr1(
        const float* __restrict__ x, int pt, int lane, int N, int PTtot) {
    int lr = lane & 15;
    int lg = lane >> 4;
    int n = pt * 16 + lr;
    float x0 = 0.f, x1 = 0.f, x2 = 0.f;
    if (pt < PTtot && n < N) { x0 = x[3*n]; x1 = x[3*n+1]; x2 = x[3*n+2]; }

    float P0 = x0*x0, P1 = x1*x1, P2 = x2*x2;
    float P3 = x0*x1, P4 = x0*x2, P5 = x1*x2;

    _Float16 h0 = (_Float16)P0, h1 = (_Float16)P1, h2 = (_Float16)P2;
    _Float16 h3 = (_Float16)P3, h4 = (_Float16)P4, h5 = (_Float16)P5;
    _Float16 h6 = (_Float16)x0, h7 = (_Float16)x1, h8 = (_Float16)x2;
    _Float16 h9 = (_Float16)1.f;
    _Float16 l0 = (_Float16)(P0 - (float)h0), l1 = (_Float16)(P1 - (float)h1);
    _Float16 l2 = (_Float16)(P2 - (float)h2), l3 = (_Float16)(P3 - (float)h3);
    _Float16 l4 = (_Float16)(P4 - (float)h4), l5 = (_Float16)(P5 - (float)h5);
    _Float16 l6 = (_Float16)(x0 - (float)h6), l7 = (_Float16)(x1 - (float)h7);
    _Float16 l8 = (_Float16)(x2 - (float)h8), l9 = (_Float16)0.f;
    _Float16 z  = (_Float16)0.f;

    half8 a;
    if      (lg == 0) a = (half8){h0,h1,h2,h3,h4,h5,h6,h7};
    else if (lg == 1) a = (half8){h8,h9,h0,h1,h2,h3,h4,h5};
    else if (lg == 2) a = (half8){h6,h7,h8,h9,l0,l1,l2,l3};
    else              a = (half8){l4,l5,l6,l7,l8,l9,z,z};
    return a;
}

#define GMF_EXPACC(CC)                                                          \
    {                                                                           \
        f32x4 y = __builtin_elementwise_fma((CC), vscale, vbias);               \
        acc.x += __uint_as_float(cvt_u32_sat(y.x));                             \
        acc.y += __uint_as_float(cvt_u32_sat(y.y));                             \
        acc.z += __uint_as_float(cvt_u32_sat(y.z));                             \
        acc.w += __uint_as_float(cvt_u32_sat(y.w));                             \
    }

// No-split main: one wave = one point-tile x ALL K. B streamed via LDS chunks.
__global__ __launch_bounds__(256, 8) void gmf_main_ns(
        const float* __restrict__ x,
        const _Float16* __restrict__ Bfh,
        float* __restrict__ out,
        int N, int KT, int PTtot) {
    __shared__ _Float16 lbs_raw[LDSTILES * 512];   // 18 KiB -> 8 blocks/CU
    const half8* lbs = (const half8*)lbs_raw;

    int tid  = threadIdx.x;
    int lane = tid & 63;
    int wid  = tid >> 6;
    int pt   = blockIdx.x * WPB + wid;   // one point-tile per wave
    bool active = pt < PTtot;

    half8 afr = gmf_build_afr1(x, pt, lane, N, PTtot);
    f32x4 acc = {0.f, 0.f, 0.f, 0.f};
    const f32x4 czero  = {0.f, 0.f, 0.f, 0.f};
    const f32x4 vscale = {EXP_SCALE, EXP_SCALE, EXP_SCALE, EXP_SCALE};
    const f32x4 vbias  = {EXP_BIAS,  EXP_BIAS,  EXP_BIAS,  EXP_BIAS};

    int nchunks = (KT + CHUNK - 1) / CHUNK;
    for (int c = 0; c < nchunks; ++c) {
        int kbase = c * CHUNK;
        int nk = min(CHUNK, KT - kbase);   // uniform across block

        __syncthreads();   // all waves done reading previous chunk

        // Stage nk tiles via global_load_lds: wave wid covers tiles wid*4+j.
        // Per call: LDS dest = wave-uniform base + lane*16B (HW requirement);
        // global src is per-lane. Zero staging VGPRs.
        #pragma unroll
        for (int j = 0; j < 4; ++j) {
            int tile = wid * 4 + j;
            if (tile < nk) {   // wave-uniform branch
                const _Float16* src = Bfh + ((size_t)(kbase + tile)) * 512 + lane * 8;
                __builtin_amdgcn_global_load_lds(
                    (const __attribute__((address_space(1))) void*)src,
                    (__attribute__((address_space(3))) void*)(lbs_raw + tile * 512 + lane * 8),
                    16, 0, 0);
            }
        }
        __syncthreads();   // implicit s_waitcnt vmcnt(0) lgkmcnt(0) drain

        if (active) {
            // 2-stage pipeline: EXPACC of tile i under shadow of tile i+1's MFMA.
            // Prefetch indices reach nk+1 <= 17 < LDSTILES (pad; values unused).
            half8 b1 = lbs[lane];
            f32x4 cP = __builtin_amdgcn_mfma_f32_16x16x32_f16(afr, b1, czero, 0, 0, 0);
            b1 = lbs[64 + lane];
            f32x4 cQ;

            int j = 1;
            for (; j + 1 < nk; j += 2) {
                half8 bA = b1;                          // tile j
                half8 bB = lbs[(j + 1) * 64 + lane];    // tile j+1
                b1 = lbs[(j + 2) * 64 + lane];          // tile j+2 (pad-safe)
                cQ = __builtin_amdgcn_mfma_f32_16x16x32_f16(afr, bA, czero, 0, 0, 0);
                GMF_EXPACC(cP)
                cP = __builtin_amdgcn_mfma_f32_16x16x32_f16(afr, bB, czero, 0, 0, 0);
                GMF_EXPACC(cQ)
            }
            if (j < nk) {                 // even nk: leftover tile in b1
                cQ = __builtin_amdgcn_mfma_f32_16x16x32_f16(afr, b1, czero, 0, 0, 0);
                GMF_EXPACC(cP)
                GMF_EXPACC(cQ)
            } else {                      // odd nk
                GMF_EXPACC(cP)
            }
        }
    }

    if (active) {
        int lr = lane & 15;
        int lg = lane >> 4;
        f32x4 a = acc;
        #pragma unroll
        for (int m = 1; m <= 8; m <<= 1) {   // reduce over 16 cols
            a.x += __shfl_xor(a.x, m);
            a.y += __shfl_xor(a.y, m);
            a.z += __shfl_xor(a.z, m);
            a.w += __shfl_xor(a.w, m);
        }
        if (lr == 0) {
            int n0 = pt * 16 + lg * 4;
            if (n0     < N) out[n0]     = a.x;
            if (n0 + 1 < N) out[n0 + 1] = a.y;
            if (n0 + 2 < N) out[n0 + 2] = a.z;
            if (n0 + 3 < N) out[n0 + 3] = a.w;
        }
    }
}

extern "C" void kernel_launch(void* const* d_in, const int* in_sizes, int n_in,
                              void* d_out, int out_size, void* d_ws, size_t ws_size,
                              hipStream_t stream) {
    const float* x          = (const float*)d_in[0];
    const float* means      = (const float*)d_in[1];
    const float* log_scales = (const float*)d_in[2];
    const float* quats      = (const float*)d_in[3];
    const float* log_amps   = (const float*)d_in[4];
    float* out = (float*)d_out;

    int K = in_sizes[4];
    int N = out_size;
    int KT = (K + 15) / 16;
    int PTtot = (N + 15) / 16;

    _Float16* Bf = (_Float16*)d_ws;   // KT tiles x 1KB

    gmf_precompute<<<(KT*16 + 255) / 256, 256, 0, stream>>>(
        means, log_scales, quats, log_amps, Bf, K, KT);

    int blocks = (PTtot + WPB - 1) / WPB;   // one point-tile per wave
    gmf_main_ns<<<blocks, 256, 0, stream>>>(x, Bf, out, N, KT, PTtot);
}

// Round 17
// 42.194 us; speedup vs baseline: 1.2956x; 1.0130x over previous
//
#include <hip/hip_runtime.h>
#include <math.h>

// out[n] = sum_k exp2( t[n,k] ),  t[n,k] = sum_{j<10} P[n,j]*G[k,j]
// P = (x0^2,x1^2,x2^2, x0x1,x0x2,x1x2, x0,x1,x2, 1)
// G = h*(A00,A11,A22), 2h*(A01,A02,A12), L2E*(b0,b1,b2), h*c + log2(amp), h=-0.5*log2(e)
//
// MFMA f16 split-2 trick (one mfma_f32_16x16x32_f16 per 16x16 tile):
//   A cols [0..31] = [Phi(10) | Phi(10) | Plo(10) | 0 0]
//   B rows [0..31] = [Ghi(10) | Glo(10) | Ghi(10) | 0 0]
//
// exp2 via mean-zero Schraudolph: y = fma(t,2^23,B); v_cvt_u32_f32 saturates
// y<0 -> 0 (incl. -60000 pad gaussians); acc += bitcast<float>(u).
//
// ROUND 17 KEY CHANGES (both target exposed latency under phase-aligned waves):
// 1. DOUBLE-BUFFERED LDS staging: stage chunk c+1 (global_load_lds, no wait)
//    BEFORE computing chunk c; the compiler's vmcnt(0) drain before s_barrier
//    then lands AFTER compute -> load latency hides under ~8 MFMA bodies.
//    One barrier per chunk (r16 had two + serial drain).
// 2. 3-DEEP MFMA pipeline, full-unrolled for nk==CHUNK: c[i]=MFMA(tile i);
//    EXPACC(c[i-2]) -> consumption trails issue by ~2 stages (~60cy),
//    covering MFMA result latency in-wave. All indices compile-time.

typedef _Float16 half8 __attribute__((ext_vector_type(8)));
typedef float    f32x4 __attribute__((ext_vector_type(4)));

#define WPB     4    // waves per block (1 point-tile per wave)
#define CHUNK   8    // k-tiles per LDS buffer
#define NBUF    2    // double buffer

#define EXP_SCALE 8388608.0f        // 2^23
#define EXP_BIAS  1064880938.0f     // (127 - 0.0563) * 2^23, mean-zero bias

__device__ __forceinline__ unsigned cvt_u32_sat(float y) {
    unsigned u;
    asm("v_cvt_u32_f32 %0, %1" : "=v"(u) : "v"(y));   // saturates: y<0 -> 0
    return u;
}

__global__ __launch_bounds__(256) void gmf_precompute(
        const float* __restrict__ means,
        const float* __restrict__ log_scales,
        const float* __restrict__ quats,
        const float* __restrict__ log_amps,
        _Float16* __restrict__ Bf, int K, int KT) {
    int k = blockIdx.x * blockDim.x + threadIdx.x;
    if (k >= KT * 16) return;

    float gc[10];
    if (k < K) {
        float qw = quats[4*k+0], qx = quats[4*k+1], qy = quats[4*k+2], qz = quats[4*k+3];
        float qn = rsqrtf(qw*qw + qx*qx + qy*qy + qz*qz);
        qw *= qn; qx *= qn; qy *= qn; qz *= qn;

        float r00 = 1.f - 2.f*(qy*qy + qz*qz);
        float r01 = 2.f*(qx*qy - qw*qz);
        float r02 = 2.f*(qx*qz + qw*qy);
        float r10 = 2.f*(qx*qy + qw*qz);
        float r11 = 1.f - 2.f*(qx*qx + qz*qz);
        float r12 = 2.f*(qy*qz - qw*qx);
        float r20 = 2.f*(qx*qz - qw*qy);
        float r21 = 2.f*(qy*qz + qw*qx);
        float r22 = 1.f - 2.f*(qx*qx + qy*qy);

        float s0 = fminf(fmaxf(expf(log_scales[3*k+0]), 1e-5f), 100.f);
        float s1 = fminf(fmaxf(expf(log_scales[3*k+1]), 1e-5f), 100.f);
        float s2 = fminf(fmaxf(expf(log_scales[3*k+2]), 1e-5f), 100.f);
        float v0 = s0*s0, v1 = s1*s1, v2 = s2*s2;

        float S00 = r00*r00*v0 + r01*r01*v1 + r02*r02*v2 + 1e-5f;
        float S11 = r10*r10*v0 + r11*r11*v1 + r12*r12*v2 + 1e-5f;
        float S22 = r20*r20*v0 + r21*r21*v1 + r22*r22*v2 + 1e-5f;
        float S01 = r00*r10*v0 + r01*r11*v1 + r02*r12*v2;
        float S02 = r00*r20*v0 + r01*r21*v1 + r02*r22*v2;
        float S12 = r10*r20*v0 + r11*r21*v1 + r12*r22*v2;

        float c00 = S11*S22 - S12*S12;
        float c01 = S02*S12 - S01*S22;
        float c02 = S01*S12 - S02*S11;
        float det = S00*c00 + S01*c01 + S02*c02;
        float id  = 1.f/det;
        float A00 = c00*id, A01 = c01*id, A02 = c02*id;
        float A11 = (S00*S22 - S02*S02)*id;
        float A12 = (S01*S02 - S00*S12)*id;
        float A22 = (S00*S11 - S01*S01)*id;

        float m0 = means[3*k+0], m1 = means[3*k+1], m2 = means[3*k+2];
        float b0 = A00*m0 + A01*m1 + A02*m2;
        float b1 = A01*m0 + A11*m1 + A12*m2;
        float b2 = A02*m0 + A12*m1 + A22*m2;
        float cc = b0*m0 + b1*m1 + b2*m2;

        float la = fminf(fmaxf(log_amps[k], -10.f), 6.f);
        const float L2E = 1.4426950408889634f;
        const float h = -0.5f * L2E;

        gc[0] = h*A00; gc[1] = h*A11; gc[2] = h*A22;
        gc[3] = 2.f*h*A01; gc[4] = 2.f*h*A02; gc[5] = 2.f*h*A12;
        gc[6] = L2E*b0; gc[7] = L2E*b1; gc[8] = L2E*b2;
        gc[9] = h*cc + L2E*la;
    } else {
        #pragma unroll
        for (int j = 0; j < 10; ++j) gc[j] = 0.f;
        gc[9] = -60000.f;   // pad gaussian -> saturates to 0 in fast exp2
    }

    _Float16 gh[10], gl[10];
    #pragma unroll
    for (int j = 0; j < 10; ++j) {
        gh[j] = (_Float16)gc[j];
        gl[j] = (_Float16)(gc[j] - (float)gh[j]);
    }

    int kt = k >> 4, c = k & 15;
    _Float16* dst = Bf + (size_t)kt * 64 * 8;
    #pragma unroll 32
    for (int r = 0; r < 32; ++r) {
        int lg = r >> 3, j = r & 7;
        _Float16 v = (r < 10) ? gh[r]
                   : (r < 20) ? gl[r-10]
                   : (r < 30) ? gh[r-20]
                   : (_Float16)0.f;
        dst[((size_t)lg*16 + c)*8 + j] = v;
    }
}

// ---- single-tile A-fragment builder ----
__device__ __forceinline__ half8 gmf_build_afr1(
        const float* __restrict__ x, int pt, int lane, int N, int PTtot) {
    int lr = lane & 15;
    int lg = lane >> 4;
    int n = pt * 16 + lr;
    float x0 = 0.f, x1 = 0.f, x2 = 0.f;
    if (pt < PTtot && n < N) { x0 = x[3*n]; x1 = x[3*n+1]; x2 = x[3*n+2]; }

    float P0 = x0*x0, P1 = x1*x1, P2 = x2*x2;
    float P3 = x0*x1, P4 = x0*x2, P5 = x1*x2;

    _Float16 h0 = (_Float16)P0, h1 = (_Float16)P1, h2 = (_Float16)P2;
    _Float16 h3 = (_Float16)P3, h4 = (_Float16)P4, h5 = (_Float16)P5;
    _Float16 h6 = (_Float16)x0, h7 = (_Float16)x1, h8 = (_Float16)x2;
    _Float16 h9 = (_Float16)1.f;
    _Float16 l0 = (_Float16)(P0 - (float)h0), l1 = (_Float16)(P1 - (float)h1);
    _Float16 l2 = (_Float16)(P2 - (float)h2), l3 = (_Float16)(P3 - (float)h3);
    _Float16 l4 = (_Float16)(P4 - (float)h4), l5 = (_Float16)(P5 - (float)h5);
    _Float16 l6 = (_Float16)(x0 - (float)h6), l7 = (_Float16)(x1 - (float)h7);
    _Float16 l8 = (_Float16)(x2 - (float)h8), l9 = (_Float16)0.f;
    _Float16 z  = (_Float16)0.f;

    half8 a;
    if      (lg == 0) a = (half8){h0,h1,h2,h3,h4,h5,h6,h7};
    else if (lg == 1) a = (half8){h8,h9,h0,h1,h2,h3,h4,h5};
    else if (lg == 2) a = (half8){h6,h7,h8,h9,l0,l1,l2,l3};
    else              a = (half8){l4,l5,l6,l7,l8,l9,z,z};
    return a;
}

#define GMF_EXPACC(CC)                                                          \
    {                                                                           \
        f32x4 y = __builtin_elementwise_fma((CC), vscale, vbias);               \
        acc.x += __uint_as_float(cvt_u32_sat(y.x));                             \
        acc.y += __uint_as_float(cvt_u32_sat(y.y));                             \
        acc.z += __uint_as_float(cvt_u32_sat(y.z));                             \
        acc.w += __uint_as_float(cvt_u32_sat(y.w));                             \
    }

// No-split main: one wave = one point-tile x ALL K.
// B streamed via double-buffered LDS chunks; 3-deep MFMA pipeline.
__global__ __launch_bounds__(256, 8) void gmf_main_ns(
        const float* __restrict__ x,
        const _Float16* __restrict__ Bfh,
        float* __restrict__ out,
        int N, int KT, int PTtot) {
    __shared__ _Float16 lbs_raw[NBUF * CHUNK * 512];   // 16 KiB -> 8 blocks/CU

    int tid  = threadIdx.x;
    int lane = tid & 63;
    int wid  = tid >> 6;
    int pt   = blockIdx.x * WPB + wid;   // one point-tile per wave
    bool active = pt < PTtot;

    half8 afr = gmf_build_afr1(x, pt, lane, N, PTtot);
    f32x4 acc = {0.f, 0.f, 0.f, 0.f};
    const f32x4 czero  = {0.f, 0.f, 0.f, 0.f};
    const f32x4 vscale = {EXP_SCALE, EXP_SCALE, EXP_SCALE, EXP_SCALE};
    const f32x4 vbias  = {EXP_BIAS,  EXP_BIAS,  EXP_BIAS,  EXP_BIAS};

    int nchunks = (KT + CHUNK - 1) / CHUNK;

    // Stage a chunk (nk tiles) into buffer `buf`. Wave wid covers tiles
    // wid*2+{0,1}. Per call: LDS dest = wave-uniform base + lane*16B (HW
    // requirement), global src per-lane. Zero staging VGPRs.
#define GMF_STAGE(BUF, KBASE, NK)                                               \
    {                                                                           \
        _Pragma("unroll")                                                       \
        for (int j = 0; j < 2; ++j) {                                           \
            int tile = wid * 2 + j;                                             \
            if (tile < (NK)) {   /* wave-uniform */                             \
                const _Float16* src = Bfh + ((size_t)((KBASE) + tile)) * 512    \
                                          + lane * 8;                           \
                __builtin_amdgcn_global_load_lds(                               \
                    (const __attribute__((address_space(1))) void*)src,         \
                    (__attribute__((address_space(3))) void*)                   \
                        (lbs_raw + ((BUF) * CHUNK + tile) * 512 + lane * 8),    \
                    16, 0, 0);                                                  \
            }                                                                   \
        }                                                                       \
    }

    // Prologue: stage chunk 0 into buf 0, wait for it.
    {
        int nk0 = min(CHUNK, KT);
        GMF_STAGE(0, 0, nk0)
    }
    __syncthreads();   // implicit vmcnt(0) drain before s_barrier

    for (int c = 0; c < nchunks; ++c) {
        int cb = c & 1;
        int kbase = c * CHUNK;
        int nk = min(CHUNK, KT - kbase);   // uniform across block

        // Issue next chunk's loads BEFORE compute: latency hides under MFMAs.
        if (c + 1 < nchunks) {
            int nk1 = min(CHUNK, KT - (c + 1) * CHUNK);
            GMF_STAGE(cb ^ 1, (c + 1) * CHUNK, nk1)
        }

        if (active) {
            const half8* cur = (const half8*)(lbs_raw + cb * CHUNK * 512);
            if (nk == CHUNK) {
                // Full-unrolled 3-deep pipeline: EXPACC trails MFMA by 2 stages.
                f32x4 cc[CHUNK];
                #pragma unroll
                for (int i = 0; i < CHUNK; ++i) {
                    half8 b = cur[i * 64 + lane];
                    cc[i] = __builtin_amdgcn_mfma_f32_16x16x32_f16(
                        afr, b, czero, 0, 0, 0);
                    if (i >= 2) GMF_EXPACC(cc[i - 2])
                }
                GMF_EXPACC(cc[CHUNK - 2])
                GMF_EXPACC(cc[CHUNK - 1])
            } else {
                // Tail chunk (dynamic nk): simple loop.
                for (int i = 0; i < nk; ++i) {
                    half8 b = cur[i * 64 + lane];
                    f32x4 cc = __builtin_amdgcn_mfma_f32_16x16x32_f16(
                        afr, b, czero, 0, 0, 0);
                    GMF_EXPACC(cc)
                }
            }
        }

        // One barrier per chunk: drains next-chunk loads (vmcnt(0) before
        // s_barrier) AND guarantees all waves finished reading buf cb before
        // it is overwritten in iteration c+1.
        __syncthreads();
    }

    if (active) {
        int lr = lane & 15;
        int lg = lane >> 4;
        f32x4 a = acc;
        #pragma unroll
        for (int m = 1; m <= 8; m <<= 1) {   // reduce over 16 cols
            a.x += __shfl_xor(a.x, m);
            a.y += __shfl_xor(a.y, m);
            a.z += __shfl_xor(a.z, m);
            a.w += __shfl_xor(a.w, m);
        }
        if (lr == 0) {
            int n0 = pt * 16 + lg * 4;
            if (n0     < N) out[n0]     = a.x;
            if (n0 + 1 < N) out[n0 + 1] = a.y;
            if (n0 + 2 < N) out[n0 + 2] = a.z;
            if (n0 + 3 < N) out[n0 + 3] = a.w;
        }
    }
#undef GMF_STAGE
}

extern "C" void kernel_launch(void* const* d_in, const int* in_sizes, int n_in,
                              void* d_out, int out_size, void* d_ws, size_t ws_size,
                              hipStream_t stream) {
    const float* x          = (const float*)d_in[0];
    const float* means      = (const float*)d_in[1];
    const float* log_scales = (const float*)d_in[2];
    const float* quats      = (const float*)d_in[3];
    const float* log_amps   = (const float*)d_in[4];
    float* out = (float*)d_out;

    int K = in_sizes[4];
    int N = out_size;
    int KT = (K + 15) / 16;
    int PTtot = (N + 15) / 16;

    _Float16* Bf = (_Float16*)d_ws;   // KT tiles x 1KB

    gmf_precompute<<<(KT*16 + 255) / 256, 256, 0, stream>>>(
        means, log_scales, quats, log_amps, Bf, K, KT);

    int blocks = (PTtot + WPB - 1) / WPB;   // one point-tile per wave
    gmf_main_ns<<<blocks, 256, 0, stream>>>(x, Bf, out, N, KT, PTtot);
}